// Round 1
// baseline (65.709 us; speedup 1.0000x reference)
//
#include <hip/hip_runtime.h>

#define N 1024
#define HD 64
#define MD 32

// ---------------------------------------------------------------------------
// h0 = features + positional encoding
// ---------------------------------------------------------------------------
__global__ void k_h0(const float* __restrict__ feat, float* __restrict__ h0)
{
    int idx = blockIdx.x * blockDim.x + threadIdx.x;   // N*HD threads
    int n = idx >> 6;
    int d = idx & 63;
    int t2 = d >> 1;
    // div = exp((2*t2) * (-ln(10000)/64))
    float div = expf((float)(2 * t2) * (-9.210340371976184f / 64.0f));
    float ang = (float)n * div;
    float pe = (d & 1) ? cosf(ang) : sinf(ang);
    h0[idx] = feat[idx] + pe;
}

// ---------------------------------------------------------------------------
// A[n][m] = h[n] . w_msg[m, 0:64]      (used with index j)
// Bb[n][m] = h[n] . w_msg[m, 64:128] + b_msg[m]   (used with index i)
// ---------------------------------------------------------------------------
__global__ void k_ab(const float* __restrict__ h, const float* __restrict__ w_msg,
                     const float* __restrict__ b_msg,
                     float* __restrict__ A, float* __restrict__ Bb)
{
    int idx = blockIdx.x * blockDim.x + threadIdx.x;   // N*MD threads
    int n = idx >> 5;
    int m = idx & 31;
    const float* hrow = h + n * HD;
    const float* wa = w_msg + m * (2 * HD + 1);
    const float* wb = wa + HD;
    float sa = 0.0f;
    float sb = b_msg[m];
#pragma unroll
    for (int c = 0; c < HD; c++) {
        float hv = hrow[c];
        sa = fmaf(hv, wa[c], sa);
        sb = fmaf(hv, wb[c], sb);
    }
    A[idx] = sa;
    Bb[idx] = sb;
}

// ---------------------------------------------------------------------------
// Pair interaction: one wave (64 lanes) per row i; lane covers j = it*64+lane.
//   m_k  = relu(A[j][k] + Bi[k] + d2 * wd[k])
//   acc += (m . w_pos[c] + b_pos[c]) * r_c        summed over j
//   msum += m                                      (layer 1 only)
// x_out[i] = x[i] + acc / (N-1)
// Diagonal j==i: r=0 kills the position term; only msum needs the correction,
// done post-loop by the single lane that owned j==i.
// ---------------------------------------------------------------------------
template<int WRITE_MSUM>
__global__ __launch_bounds__(64) void k_pair(
    const float* __restrict__ x, const float* __restrict__ A,
    const float* __restrict__ Bb, const float* __restrict__ w_msg,
    const float* __restrict__ w_pos, const float* __restrict__ b_pos,
    float* __restrict__ x_out, float* __restrict__ msum_out)
{
    const int i = blockIdx.x;
    const int lane = threadIdx.x;

    __shared__ float red[MD][68];

    const float xi0 = x[i * 3 + 0];
    const float xi1 = x[i * 3 + 1];
    const float xi2 = x[i * 3 + 2];

    float Bi[MD], wd[MD], wp0[MD], wp1[MD], wp2[MD];
#pragma unroll
    for (int k = 0; k < MD; k++) {
        Bi[k]  = Bb[i * MD + k];
        wd[k]  = w_msg[k * (2 * HD + 1) + 2 * HD];
        wp0[k] = w_pos[k];
        wp1[k] = w_pos[MD + k];
        wp2[k] = w_pos[2 * MD + k];
    }
    const float bp0 = b_pos[0], bp1 = b_pos[1], bp2 = b_pos[2];

    float msum[MD];
    if (WRITE_MSUM) {
#pragma unroll
        for (int k = 0; k < MD; k++) msum[k] = 0.0f;
    }
    float acc0 = 0.0f, acc1 = 0.0f, acc2 = 0.0f;

    for (int it = 0; it < N / 64; it++) {
        const int j = it * 64 + lane;

        float a[MD];
        const float4* arow = (const float4*)(A + j * MD);
#pragma unroll
        for (int q = 0; q < MD / 4; q++) {
            float4 v = arow[q];
            a[4 * q + 0] = v.x;
            a[4 * q + 1] = v.y;
            a[4 * q + 2] = v.z;
            a[4 * q + 3] = v.w;
        }
        const float xj0 = x[j * 3 + 0];
        const float xj1 = x[j * 3 + 1];
        const float xj2 = x[j * 3 + 2];

        const float rx = xj0 - xi0;
        const float ry = xj1 - xi1;
        const float rz = xj2 - xi2;
        const float d2 = fmaf(rx, rx, fmaf(ry, ry, rz * rz));

        float s0 = 0.0f, s1 = 0.0f, s2 = 0.0f;
#pragma unroll
        for (int k = 0; k < MD; k++) {
            float t = fmaf(d2, wd[k], a[k] + Bi[k]);
            float m = fmaxf(t, 0.0f);
            if (WRITE_MSUM) msum[k] += m;
            s0 = fmaf(m, wp0[k], s0);
            s1 = fmaf(m, wp1[k], s1);
            s2 = fmaf(m, wp2[k], s2);
        }
        acc0 = fmaf(s0 + bp0, rx, acc0);
        acc1 = fmaf(s1 + bp1, ry, acc1);
        acc2 = fmaf(s2 + bp2, rz, acc2);
    }

    if (WRITE_MSUM) {
        // remove diagonal contribution (d2 = 0 at j == i)
        if (lane == (i & 63)) {
#pragma unroll
            for (int k = 0; k < MD; k++) {
                float t = A[i * MD + k] + Bi[k];
                msum[k] -= fmaxf(t, 0.0f);
            }
        }
    }

    // reduce acc across 64 lanes
#pragma unroll
    for (int off = 32; off > 0; off >>= 1) {
        acc0 += __shfl_xor(acc0, off);
        acc1 += __shfl_xor(acc1, off);
        acc2 += __shfl_xor(acc2, off);
    }
    if (lane == 0) {
        x_out[i * 3 + 0] = xi0 + acc0 / 1023.0f;
        x_out[i * 3 + 1] = xi1 + acc1 / 1023.0f;
        x_out[i * 3 + 2] = xi2 + acc2 / 1023.0f;
    }

    if (WRITE_MSUM) {
        // transpose-reduce 32 per-lane partial sums via LDS
#pragma unroll
        for (int k = 0; k < MD; k++) red[k][lane] = msum[k];
        __syncthreads();
        if (lane < MD) {
            const float4* row = (const float4*)&red[lane][0];
            float s = 0.0f;
#pragma unroll
            for (int q = 0; q < 16; q++) {
                float4 v = row[q];
                s += (v.x + v.y) + (v.z + v.w);
            }
            msum_out[i * MD + lane] = s;
        }
    }
}

// ---------------------------------------------------------------------------
// h_out = relu( [h, msum] @ w_feat.T + b_feat )
// ---------------------------------------------------------------------------
__global__ void k_h(const float* __restrict__ h, const float* __restrict__ msum,
                    const float* __restrict__ wf, const float* __restrict__ bf,
                    float* __restrict__ h_out)
{
    int idx = blockIdx.x * blockDim.x + threadIdx.x;   // N*HD threads
    int n = idx >> 6;
    int o = idx & 63;
    const float* hrow = h + n * HD;
    const float* mrow = msum + n * MD;
    const float* w = wf + o * (HD + MD);
    float s = bf[o];
#pragma unroll
    for (int c = 0; c < HD; c++) s = fmaf(hrow[c], w[c], s);
#pragma unroll
    for (int k = 0; k < MD; k++) s = fmaf(mrow[k], w[HD + k], s);
    h_out[idx] = fmaxf(s, 0.0f);
}

// ---------------------------------------------------------------------------
extern "C" void kernel_launch(void* const* d_in, const int* in_sizes, int n_in,
                              void* d_out, int out_size, void* d_ws, size_t ws_size,
                              hipStream_t stream)
{
    const float* pos     = (const float*)d_in[0];
    const float* feat    = (const float*)d_in[1];
    const float* w_msg1  = (const float*)d_in[3];
    const float* b_msg1  = (const float*)d_in[4];
    const float* w_pos1  = (const float*)d_in[5];
    const float* b_pos1  = (const float*)d_in[6];
    const float* w_feat1 = (const float*)d_in[7];
    const float* b_feat1 = (const float*)d_in[8];
    const float* w_msg2  = (const float*)d_in[9];
    const float* b_msg2  = (const float*)d_in[10];
    const float* w_pos2  = (const float*)d_in[11];
    const float* b_pos2  = (const float*)d_in[12];

    float* ws  = (float*)d_ws;
    float* h0  = ws;                 // N*HD   = 65536
    float* A1  = h0  + N * HD;       // N*MD   = 32768
    float* B1  = A1  + N * MD;       // N*MD
    float* x1  = B1  + N * MD;       // N*4 (padded)
    float* ms1 = x1  + N * 4;        // N*MD
    float* h1  = ms1 + N * MD;       // N*HD
    float* A2  = h1  + N * HD;       // N*MD
    float* B2  = A2  + N * MD;       // N*MD

    k_h0<<<(N * HD) / 256, 256, 0, stream>>>(feat, h0);
    k_ab<<<(N * MD) / 256, 256, 0, stream>>>(h0, w_msg1, b_msg1, A1, B1);
    k_pair<1><<<N, 64, 0, stream>>>(pos, A1, B1, w_msg1, w_pos1, b_pos1, x1, ms1);
    k_h<<<(N * HD) / 256, 256, 0, stream>>>(h0, ms1, w_feat1, b_feat1, h1);
    k_ab<<<(N * MD) / 256, 256, 0, stream>>>(h1, w_msg2, b_msg2, A2, B2);
    k_pair<0><<<N, 64, 0, stream>>>(x1, A2, B2, w_msg2, w_pos2, b_pos2,
                                    (float*)d_out, nullptr);
}